// Round 4
// baseline (314.719 us; speedup 1.0000x reference)
//
#include <hip/hip_runtime.h>
#include <hip/hip_fp16.h>
#include <math.h>

#define N_NODES 30000
#define E_EDGES 480000
#define VD      512
#define HID     32
#define K1_BLOCKS 512

// ws layout (float/int index, all 4-byte elements):
//   [0, 30000)          sarr    (float, k2)
//   [30000, 32560)      part    (float, K1_BLOCKS x 5 moment partials, k1)
//   [32768, 62768)      counts  (int, memset->k1 hist)
//   [62768, 92769)      offsets (int, k2 scan; offsets[N]=E)
//   [92800, 122800)     cursors (int, k2 scan copy; consumed by k3)
//   [122880, 602880)    srcs    (int, CSR-sorted src ids, k3)
//   fp32 path: [602880, 632880) inv (float, k1)
//   fp16 path: byte 2411520+    nvis (fp16 normalized rows, 1024 B/row, k1)
#define SARR_OFF   0
#define PART_OFF   30000
#define CNT_OFF    32768
#define OFFS_OFF   62768
#define CURS_OFF   92800
#define SRCS_OFF   122880
#define INV_OFF    602880
#define NV_BYTE_OFF 2411520u

__device__ inline float2 h2f(unsigned int u) {
    const __half2 h = *reinterpret_cast<const __half2*>(&u);
    return __half22float2(h);
}

// ---------------- k1: histogram(dst) + x-moment partials + row normalize ----------------
__global__ void __launch_bounds__(256) k1_prep(const float* __restrict__ x,
                                               const float* __restrict__ visual,
                                               const int* __restrict__ ei,
                                               float* __restrict__ part,
                                               int* __restrict__ counts,
                                               float* __restrict__ ws,
                                               int fp16mode) {
    int gid    = blockIdx.x * blockDim.x + threadIdx.x;
    int stride = gridDim.x * blockDim.x;

    // --- histogram of dst ---
    for (int e = gid; e < E_EDGES; e += stride)
        atomicAdd(&counts[ei[E_EDGES + e]], 1);

    // --- moments of x ---
    __shared__ float red[4][5];
    float s0 = 0.f, s1 = 0.f, s00 = 0.f, s11 = 0.f, s01 = 0.f;
    for (int i = gid; i < N_NODES; i += stride) {
        float2 v = ((const float2*)x)[i];
        s0  += v.x;       s1  += v.y;
        s00 += v.x * v.x; s11 += v.y * v.y;
        s01 += v.x * v.y;
    }
    for (int o = 32; o; o >>= 1) {
        s0  += __shfl_xor(s0,  o, 64);
        s1  += __shfl_xor(s1,  o, 64);
        s00 += __shfl_xor(s00, o, 64);
        s11 += __shfl_xor(s11, o, 64);
        s01 += __shfl_xor(s01, o, 64);
    }
    int wv = threadIdx.x >> 6;
    if ((threadIdx.x & 63) == 0) {
        red[wv][0] = s0; red[wv][1] = s1; red[wv][2] = s00;
        red[wv][3] = s11; red[wv][4] = s01;
    }
    __syncthreads();
    if (threadIdx.x < 5) {
        part[blockIdx.x * 5 + threadIdx.x] =
            red[0][threadIdx.x] + red[1][threadIdx.x] +
            red[2][threadIdx.x] + red[3][threadIdx.x];
    }

    // --- normalize rows (wave per node) ---
    ushort* nvis = (ushort*)((char*)ws + NV_BYTE_OFF);
    float*  inv  = ws + INV_OFF;
    int wave  = gid >> 6;
    int lane  = threadIdx.x & 63;
    int nwave = stride >> 6;
    for (int node = wave; node < N_NODES; node += nwave) {
        const float4* row = (const float4*)(visual + (size_t)node * VD);
        float4 a = row[lane];
        float4 b = row[lane + 64];
        float p = a.x*a.x + a.y*a.y + a.z*a.z + a.w*a.w
                + b.x*b.x + b.y*b.y + b.z*b.z + b.w*b.w;
        for (int o = 32; o; o >>= 1) p += __shfl_xor(p, o, 64);
        float r = 1.0f / fmaxf(sqrtf(p), 1e-8f);
        if (fp16mode) {
            __half2 p0 = __floats2half2_rn(a.x * r, a.y * r);
            __half2 p1 = __floats2half2_rn(a.z * r, a.w * r);
            __half2 p2 = __floats2half2_rn(b.x * r, b.y * r);
            __half2 p3 = __floats2half2_rn(b.z * r, b.w * r);
            uint2 q0, q1;
            q0.x = *(unsigned int*)&p0; q0.y = *(unsigned int*)&p1;
            q1.x = *(unsigned int*)&p2; q1.y = *(unsigned int*)&p3;
            uint2* orow = (uint2*)(nvis + (size_t)node * VD);
            orow[lane]      = q0;
            orow[lane + 64] = q1;
        } else if (lane == 0) {
            inv[node] = r;
        }
    }
}

// ---------------- k2: block0 = exclusive scan; other blocks = sarr ----------------
__global__ void __launch_bounds__(256) k2_scan_node(
        const float* __restrict__ x,
        const float* __restrict__ w1, const float* __restrict__ b1,
        const float* __restrict__ gamma, const float* __restrict__ beta,
        const float* __restrict__ prelu_a,
        const float* __restrict__ w2, const float* __restrict__ b2,
        const float* __restrict__ wc, const float* __restrict__ wp,
        const float* __restrict__ part,
        const int* __restrict__ counts,
        int* __restrict__ offsets, int* __restrict__ cursors,
        float* __restrict__ sarr) {
    int t = threadIdx.x;
    if (blockIdx.x == 0) {
        // exclusive scan of counts[30000] with 256 threads
        __shared__ int ssum[256];
        const int chunk = (N_NODES + 255) / 256;  // 118
        int b = t * chunk;
        int e = min(b + chunk, N_NODES);
        int s = 0;
        for (int i = b; i < e; ++i) s += counts[i];
        ssum[t] = s;
        __syncthreads();
        for (int off = 1; off < 256; off <<= 1) {
            int v = (t >= off) ? ssum[t - off] : 0;
            __syncthreads();
            ssum[t] += v;
            __syncthreads();
        }
        int run = ssum[t] - s;  // exclusive base for this chunk
        for (int i = b; i < e; ++i) {
            offsets[i] = run;
            cursors[i] = run;
            run += counts[i];
        }
        if (t == 255) offsets[N_NODES] = run;
        return;
    }
    // ---- sarr ----
    __shared__ float s_scale[HID], s_shift[HID], s_u[HID], s_w1a[HID], s_w1b[HID];
    __shared__ float s_wpc[HID];
    __shared__ float s_sb;
    if (t < HID) {
        float S0 = 0, S1 = 0, S00 = 0, S11 = 0, S01 = 0;
        for (int p = 0; p < K1_BLOCKS; ++p) {
            S0  += part[p * 5 + 0];
            S1  += part[p * 5 + 1];
            S00 += part[p * 5 + 2];
            S11 += part[p * 5 + 3];
            S01 += part[p * 5 + 4];
        }
        float wpck = 0.f;
        for (int j = 0; j < HID; ++j) wpck += wp[j] * wc[j * HID + t];
        s_wpc[t] = wpck;
        const float invN = 1.0f / (float)N_NODES;
        float m0  = S0 * invN, m1 = S1 * invN;
        float v0  = fmaxf(S00 * invN - m0 * m0, 0.f);
        float v1  = fmaxf(S11 * invN - m1 * m1, 0.f);
        float c01 = S01 * invN - m0 * m1;
        float a0 = w1[2 * t], a1 = w1[2 * t + 1];
        float mean = a0 * m0 + a1 * m1 + b1[t];
        float var  = fmaxf(a0 * a0 * v0 + a1 * a1 * v1 + 2.f * a0 * a1 * c01, 0.f);
        float rs    = 1.0f / sqrtf(var + 1e-5f);
        float scale = gamma[t] * rs;
        s_scale[t] = scale;
        s_shift[t] = beta[t] - mean * scale;
        s_w1a[t] = a0; s_w1b[t] = a1;
    }
    __syncthreads();
    if (t < HID) {
        float uu = 0.f;
        for (int k = 0; k < HID; ++k) uu += s_wpc[k] * w2[k * HID + t];
        s_u[t] = uu;
    }
    if (t == 0) {
        float sb = 0.f;
        for (int k = 0; k < HID; ++k) sb += s_wpc[k] * b2[k];
        s_sb = sb;
    }
    __syncthreads();
    const float aslope = prelu_a[0];
    const float sb = s_sb;
    int i0     = (blockIdx.x - 1) * blockDim.x + t;
    int stride = (gridDim.x - 1) * blockDim.x;
    for (int i = i0; i < N_NODES; i += stride) {
        float2 xv = ((const float2*)x)[i];
        float sacc = sb;
        #pragma unroll
        for (int c = 0; c < HID; ++c) {
            float h  = s_w1a[c] * xv.x + s_w1b[c] * xv.y + b1[c];
            float tt = h * s_scale[c] + s_shift[c];
            tt = tt >= 0.f ? tt : aslope * tt;
            sacc += tt * s_u[c];
        }
        sarr[i] = sacc;
    }
}

// ---------------- k3: scatter src ids into CSR order ----------------
__global__ void __launch_bounds__(256) k3_scatter(const int* __restrict__ ei,
                                                  int* __restrict__ cursors,
                                                  int* __restrict__ srcs) {
    int gid    = blockIdx.x * blockDim.x + threadIdx.x;
    int stride = gridDim.x * blockDim.x;
    for (int e = gid; e < E_EDGES; e += stride) {
        int s = ei[e];
        int d = ei[E_EDGES + e];
        int pos = atomicAdd(&cursors[d], 1);
        srcs[pos] = s;
    }
}

// ---------------- k4 (fp16): wave per dst; acc = sum s_e * n_src; out = dot(n_dst, acc)/deg + K
__global__ void __launch_bounds__(256) k4_edge16(const int* __restrict__ offsets,
                                                 const int* __restrict__ srcs,
                                                 const float* __restrict__ ws_ro,
                                                 const float* __restrict__ sarr,
                                                 const float* __restrict__ bc,
                                                 const float* __restrict__ wp,
                                                 const float* __restrict__ bp,
                                                 float* __restrict__ out) {
    const uint4* nvis = (const uint4*)((const char*)ws_ro + NV_BYTE_OFF);
    float K = bp[0];
    #pragma unroll
    for (int j = 0; j < HID; ++j) K += wp[j] * bc[j];
    int wave  = (blockIdx.x * blockDim.x + threadIdx.x) >> 6;
    int lane  = threadIdx.x & 63;
    int nwave = (gridDim.x * blockDim.x) >> 6;
    for (int d = wave; d < N_NODES; d += nwave) {
        int beg = offsets[d];
        int end = offsets[d + 1];
        uint4 D = nvis[(size_t)d * 64 + lane];
        float2 d0 = h2f(D.x), d1 = h2f(D.y), d2 = h2f(D.z), d3 = h2f(D.w);
        float acc0 = 0.f, acc1 = 0.f, acc2 = 0.f, acc3 = 0.f;
        float acc4 = 0.f, acc5 = 0.f, acc6 = 0.f, acc7 = 0.f;
        for (int base = beg; base < end; base += 64) {
            int cnt = min(64, end - base);
            // stage this chunk's src ids + s-values, one per lane
            int   myidx = (lane < cnt) ? srcs[base + lane] : 0;
            float mys   = (lane < cnt) ? sarr[myidx] : 0.f;
            for (int j = 0; j < cnt; ++j) {
                int   s  = __shfl(myidx, j, 64);
                float sv = __shfl(mys,   j, 64);
                uint4 A = nvis[(size_t)s * 64 + lane];
                float2 a0 = h2f(A.x), a1 = h2f(A.y), a2 = h2f(A.z), a3 = h2f(A.w);
                acc0 += sv * a0.x; acc1 += sv * a0.y;
                acc2 += sv * a1.x; acc3 += sv * a1.y;
                acc4 += sv * a2.x; acc5 += sv * a2.y;
                acc6 += sv * a3.x; acc7 += sv * a3.y;
            }
        }
        float p = acc0 * d0.x + acc1 * d0.y + acc2 * d1.x + acc3 * d1.y
                + acc4 * d2.x + acc5 * d2.y + acc6 * d3.x + acc7 * d3.y;
        for (int o = 32; o; o >>= 1) p += __shfl_xor(p, o, 64);
        if (lane == 0)
            out[d] = p / fmaxf((float)(end - beg), 1.0f) + K;
    }
}

// ---------------- k4 (fp32 fallback): raw visual rows + inv norms ----------------
__global__ void __launch_bounds__(256) k4_edge32(const int* __restrict__ offsets,
                                                 const int* __restrict__ srcs,
                                                 const float* __restrict__ visual,
                                                 const float* __restrict__ inv,
                                                 const float* __restrict__ sarr,
                                                 const float* __restrict__ bc,
                                                 const float* __restrict__ wp,
                                                 const float* __restrict__ bp,
                                                 float* __restrict__ out) {
    float K = bp[0];
    #pragma unroll
    for (int j = 0; j < HID; ++j) K += wp[j] * bc[j];
    int wave  = (blockIdx.x * blockDim.x + threadIdx.x) >> 6;
    int lane  = threadIdx.x & 63;
    int nwave = (gridDim.x * blockDim.x) >> 6;
    for (int d = wave; d < N_NODES; d += nwave) {
        int beg = offsets[d];
        int end = offsets[d + 1];
        const float4* drow = (const float4*)(visual + (size_t)d * VD);
        float4 D0 = drow[lane];
        float4 D1 = drow[lane + 64];
        float acc[8] = {0.f};
        for (int base = beg; base < end; base += 64) {
            int cnt = min(64, end - base);
            int   myidx = (lane < cnt) ? srcs[base + lane] : 0;
            float mys   = (lane < cnt) ? sarr[myidx] * inv[myidx] : 0.f;
            for (int j = 0; j < cnt; ++j) {
                int   s  = __shfl(myidx, j, 64);
                float sv = __shfl(mys,   j, 64);
                const float4* srow = (const float4*)(visual + (size_t)s * VD);
                float4 A0 = srow[lane];
                float4 A1 = srow[lane + 64];
                acc[0] += sv * A0.x; acc[1] += sv * A0.y;
                acc[2] += sv * A0.z; acc[3] += sv * A0.w;
                acc[4] += sv * A1.x; acc[5] += sv * A1.y;
                acc[6] += sv * A1.z; acc[7] += sv * A1.w;
            }
        }
        float p = acc[0] * D0.x + acc[1] * D0.y + acc[2] * D0.z + acc[3] * D0.w
                + acc[4] * D1.x + acc[5] * D1.y + acc[6] * D1.z + acc[7] * D1.w;
        for (int o = 32; o; o >>= 1) p += __shfl_xor(p, o, 64);
        if (lane == 0)
            out[d] = p * inv[d] / fmaxf((float)(end - beg), 1.0f) + K;
    }
}

extern "C" void kernel_launch(void* const* d_in, const int* in_sizes, int n_in,
                              void* d_out, int out_size, void* d_ws, size_t ws_size,
                              hipStream_t stream) {
    const float* x       = (const float*)d_in[0];
    const float* visual  = (const float*)d_in[1];
    const int*   ei      = (const int*)  d_in[2];
    const float* w1      = (const float*)d_in[3];
    const float* b1      = (const float*)d_in[4];
    const float* gamma   = (const float*)d_in[5];
    const float* beta    = (const float*)d_in[6];
    const float* prelu_a = (const float*)d_in[7];
    const float* w2      = (const float*)d_in[8];
    const float* b2      = (const float*)d_in[9];
    const float* wc      = (const float*)d_in[10];
    const float* bc      = (const float*)d_in[11];
    const float* wp      = (const float*)d_in[12];
    const float* bp      = (const float*)d_in[13];
    float* out = (float*)d_out;

    float* ws      = (float*)d_ws;
    float* sarr    = ws + SARR_OFF;
    float* part    = ws + PART_OFF;
    int*   counts  = (int*)(ws + CNT_OFF);
    int*   offsets = (int*)(ws + OFFS_OFF);
    int*   cursors = (int*)(ws + CURS_OFF);
    int*   srcs    = (int*)(ws + SRCS_OFF);
    float* inv     = ws + INV_OFF;

    bool fp16ok = ws_size >= (size_t)NV_BYTE_OFF + (size_t)N_NODES * VD * 2;

    hipMemsetAsync(counts, 0, N_NODES * sizeof(int), stream);
    k1_prep<<<K1_BLOCKS, 256, 0, stream>>>(x, visual, ei, part, counts, ws,
                                           fp16ok ? 1 : 0);
    k2_scan_node<<<256, 256, 0, stream>>>(x, w1, b1, gamma, beta, prelu_a,
                                          w2, b2, wc, wp, part, counts,
                                          offsets, cursors, sarr);
    k3_scatter<<<512, 256, 0, stream>>>(ei, cursors, srcs);
    if (fp16ok) {
        k4_edge16<<<1024, 256, 0, stream>>>(offsets, srcs, ws, sarr, bc, wp, bp, out);
    } else {
        k4_edge32<<<1024, 256, 0, stream>>>(offsets, srcs, visual, inv, sarr,
                                            bc, wp, bp, out);
    }
}